// Round 8
// baseline (520.771 us; speedup 1.0000x reference)
//
#include <hip/hip_runtime.h>

// MeshGNN: 6-layer GCN on 100k nodes / 1.6M edges, HIDDEN=128.
// Round 8: padded-CSR single-pass build (csr_pad[d*64+rank]=s; kills fill2,
// scans, rank[], rowptr). Rows padded to 16-multiples with sentinel src=N
// (G row N zeroed) -> uniform gather trips, no tails. g4dec ported to
// quarter-split half8 gather. gather6/gather3 use padded CSR (stop at deg).

#define HID 128
#define MAXDEG 64

typedef __attribute__((ext_vector_type(4))) float f32x4;
typedef __attribute__((ext_vector_type(8))) short bf16x8;
typedef __attribute__((ext_vector_type(8))) _Float16 half8;

__device__ __forceinline__ long long ld_idx(const void* p, long long i, int is64) {
    if (is64) return ((const long long*)p)[i];
    return (long long)((const int*)p)[i];
}

__device__ __forceinline__ unsigned short f2bf(float v) {
    unsigned u = __float_as_uint(v);
    unsigned r = (u + 0x7fffu + ((u >> 16) & 1u)) >> 16;
    return (unsigned short)r;
}
__device__ __forceinline__ float bf2f(unsigned short h) {
    return __uint_as_float(((unsigned)h) << 16);
}

// Probe int64 vs int32 edge layout (parallel: 64 lanes x 2 odd words each).
__global__ void detect_kernel(const unsigned int* e, long long nwords, int* flag) {
    int t = threadIdx.x;
    unsigned v = 0;
    long long i0 = 1 + 2 * (long long)t;
    long long i1 = 1 + 2 * (long long)(t + 64);
    if (i0 < nwords && i0 < 256) v |= e[i0];
    if (i1 < nwords && i1 < 256) v |= e[i1];
    int any = __any(v != 0u);
    if (t == 0) *flag = any ? 0 : 1;
}

// single-pass padded-CSR build: histogram + placement in one atomic pass
__global__ void build_kernel(const void* eidx, long long E, const int* flag,
                             int* __restrict__ cnt, int* __restrict__ csr) {
    long long i = (long long)blockIdx.x * blockDim.x + threadIdx.x;
    if (i >= E) return;
    int is64 = *flag;
    int s = (int)ld_idx(eidx, i, is64);
    int d = (int)ld_idx(eidx, E + i, is64);
    int r = atomicAdd(&cnt[d], 1);
    if (r < MAXDEG) csr[((long long)d << 6) + r] = s;
}

// per node: dinv = rsqrt(cnt+1); pad csr row to 16-multiple with sentinel N
__global__ void dinvpad_kernel(const int* __restrict__ cnt, float* __restrict__ dinv,
                               int* __restrict__ csr, int N) {
    int i = blockIdx.x * blockDim.x + threadIdx.x;
    if (i >= N) return;
    int c = cnt[i];
    dinv[i] = rsqrtf((float)c + 1.0f);
    int deg = c < MAXDEG ? c : MAXDEG;
    int trips = (deg + 15) & ~15;
    int* row = csr + ((long long)i << 6);
    for (int r = deg; r < trips; ++r) row[r] = N;   // sentinel: zero G row
}

// encoder aggregation (6-wide), thread per dst (stops at true deg; no pads)
__global__ void gather6_kernel(const int* __restrict__ cnt, const int* __restrict__ csr,
                               const float* __restrict__ x, const float* __restrict__ dinv,
                               float* __restrict__ aggV, int N) {
    int i = blockIdx.x * blockDim.x + threadIdx.x;
    if (i >= N) return;
    int deg = cnt[i]; deg = deg < MAXDEG ? deg : MAXDEG;
    const int* row = csr + ((long long)i << 6);
    float di = dinv[i];
    const float* xi = x + (long long)i * 6;
    float a0 = xi[0] * di, a1 = xi[1] * di, a2 = xi[2] * di;
    float a3 = xi[3] * di, a4 = xi[4] * di, a5 = xi[5] * di;
    for (int j = 0; j < deg; ++j) {
        int src = row[j];
        float ds = dinv[src];
        const float* xs = x + (long long)src * 6;
        a0 += xs[0] * ds; a1 += xs[1] * ds; a2 += xs[2] * ds;
        a3 += xs[3] * ds; a4 += xs[4] * ds; a5 += xs[5] * ds;
    }
    float* o = aggV + (long long)i * 6;
    o[0] = a0 * di; o[1] = a1 * di; o[2] = a2 * di;
    o[3] = a3 * di; o[4] = a4 * di; o[5] = a5 * di;
}

// W_hid -> fragment-ordered split-bf16 (unchanged layout)
__global__ void wprep_kernel(const float* __restrict__ W, unsigned short* __restrict__ Wf) {
    int idx = blockIdx.x * 256 + threadIdx.x;
    if (idx >= 16384) return;
    int j = idx & 7;
    int lane = (idx >> 3) & 63;
    int ks = (idx >> 9) & 3;
    int nt = idx >> 11;
    int c = (nt << 4) + (lane & 15);
    int k = (ks << 5) + ((lane >> 4) << 3) + j;
    float v = W[k * 128 + c];
    unsigned short hi = f2bf(v);
    unsigned short lo = f2bf(v - bf2f(hi));
    Wf[idx] = hi;
    Wf[idx + 16384] = lo;
}

// ---- shared device pieces ----

// quarter-split padded gather: lane (q=lane>>4, l16=lane&15) owns 8 cols of
// srcs with slot ≡ q (mod 4); 16B half8 loads; uniform trips, no tail.
// Returns per-lane partial (combine with shfl_xor 16,32 afterwards).
struct Acc8 { float a[8]; };
__device__ __forceinline__ Acc8 gather_q(const int* __restrict__ cnt,
                                         const int* __restrict__ csr,
                                         const half8* __restrict__ G8,
                                         long long node, int q, int l16) {
    Acc8 r;
#pragma unroll
    for (int k = 0; k < 8; ++k) r.a[k] = 0.f;
    int deg = cnt[node]; deg = deg < MAXDEG ? deg : MAXDEG;
    int trips = (deg + 15) >> 4;
    const int* cs = csr + (node << 6) + q;
    if (q == 0) {                       // self term on quarter 0
        half8 sv = G8[node * 16 + l16];
#pragma unroll
        for (int k = 0; k < 8; ++k) r.a[k] = (float)sv[k];
    }
    for (int it = 0; it < trips; ++it) {
        int i0 = cs[0], i1 = cs[4], i2 = cs[8], i3 = cs[12];
        half8 v0 = G8[(long long)i0 * 16 + l16];
        half8 v1 = G8[(long long)i1 * 16 + l16];
        half8 v2 = G8[(long long)i2 * 16 + l16];
        half8 v3 = G8[(long long)i3 * 16 + l16];
#pragma unroll
        for (int k = 0; k < 8; ++k)
            r.a[k] += ((float)v0[k] + (float)v1[k]) + ((float)v2[k] + (float)v3[k]);
        cs += 16;
    }
    return r;
}

// MFMA phase: 16 rows (LDS split-bf16) x W_hid-fragments -> Gout fp16, x dinv[row]
__device__ __forceinline__ void mfma_phase(const unsigned short* Ahi, const unsigned short* Alo,
                                           const unsigned short* __restrict__ Wf,
                                           const float* dinvS, _Float16* __restrict__ Gout,
                                           long long base, int N, int w, int lane) {
    int arow = lane & 15;
    int abase = arow * 128;
    f32x4 acc = {};
    const bf16x8* Bf = (const bf16x8*)Wf;
#pragma unroll
    for (int ks = 0; ks < 4; ++ks) {
        int slot = (ks << 2) + (lane >> 4);
        int aoff = abase + ((slot ^ (arow & 7)) << 3);
        bf16x8 ah = *(const bf16x8*)&Ahi[aoff];
        bf16x8 al = *(const bf16x8*)&Alo[aoff];
        int g = (((w << 2) + ks) << 6) + lane;
        bf16x8 bh = Bf[g];
        bf16x8 bl = Bf[g + 2048];
        acc = __builtin_amdgcn_mfma_f32_16x16x32_bf16(ah, bh, acc, 0, 0, 0);
        acc = __builtin_amdgcn_mfma_f32_16x16x32_bf16(ah, bl, acc, 0, 0, 0);
        acc = __builtin_amdgcn_mfma_f32_16x16x32_bf16(al, bh, acc, 0, 0, 0);
    }
    int rbase = (lane >> 4) << 2;
    int col = (w << 4) + (lane & 15);
#pragma unroll
    for (int r = 0; r < 4; ++r) {
        int lrow = rbase + r;
        long long grow = base + lrow;
        if (grow < N) Gout[grow * HID + col] = (_Float16)(acc[r] * dinvS[lrow]);
    }
}

// parity split-write (8B per half), used by encF
__device__ __forceinline__ void split_write(unsigned short* Ahi, unsigned short* Alo,
                                            float4 h, int lrow, int l32, int half) {
    unsigned short h0 = f2bf(h.x), h1 = f2bf(h.y), h2 = f2bf(h.z), h3 = f2bf(h.w);
    int slot = l32 >> 1;
    int off = lrow * 128 + (((slot ^ (lrow & 7)) << 3) | ((l32 & 1) << 2));
    if (half == 0) {
        *(uint2*)&Ahi[off] = make_uint2((unsigned)h0 | ((unsigned)h1 << 16),
                                        (unsigned)h2 | ((unsigned)h3 << 16));
    } else {
        unsigned short l0 = f2bf(h.x - bf2f(h0));
        unsigned short l1 = f2bf(h.y - bf2f(h1));
        unsigned short l2 = f2bf(h.z - bf2f(h2));
        unsigned short l3 = f2bf(h.w - bf2f(h3));
        *(uint2*)&Alo[off] = make_uint2((unsigned)l0 | ((unsigned)l1 << 16),
                                        (unsigned)l2 | ((unsigned)l3 << 16));
    }
}

// encF: h0 = relu(aggV @ W_enc + b_enc); G1 = (h0 @ W_hid) * dinv  (16 nodes/block)
__global__ __launch_bounds__(512) void encF_kernel(const float* __restrict__ aggV,
                                                   const float* __restrict__ Wenc,
                                                   const float* __restrict__ benc,
                                                   const unsigned short* __restrict__ Wf,
                                                   const float* __restrict__ dinv,
                                                   _Float16* __restrict__ Gout, int N) {
    __shared__ unsigned short Ahi[16 * 128];
    __shared__ unsigned short Alo[16 * 128];
    __shared__ float WencS[6 * 128];
    __shared__ float dinvS[16];
    int tid = threadIdx.x;
    for (int i = tid; i < 768; i += 512) WencS[i] = Wenc[i];
    __syncthreads();
    int w = tid >> 6, lane = tid & 63, half = lane >> 5, l32 = lane & 31;
    long long base = (long long)blockIdx.x * 16;
#pragma unroll
    for (int rr = 0; rr < 2; ++rr) {
        int lrow = w + rr * 8;
        long long node = base + lrow;
        float4 h = make_float4(0.f, 0.f, 0.f, 0.f);
        float di = 0.f;
        if (node < N) {
            di = dinv[node];
            const float* av = aggV + node * 6;
            float a0 = av[0], a1 = av[1], a2 = av[2], a3 = av[3], a4 = av[4], a5 = av[5];
            float4 bb = *(const float4*)&benc[l32 * 4];
            int c = l32 * 4;
            h = bb;
#define EK(AK, K)                                                   \
            h.x = fmaf(AK, WencS[(K) * 128 + c + 0], h.x);          \
            h.y = fmaf(AK, WencS[(K) * 128 + c + 1], h.y);          \
            h.z = fmaf(AK, WencS[(K) * 128 + c + 2], h.z);          \
            h.w = fmaf(AK, WencS[(K) * 128 + c + 3], h.w);
            EK(a0, 0) EK(a1, 1) EK(a2, 2) EK(a3, 3) EK(a4, 4) EK(a5, 5)
#undef EK
            h.x = fmaxf(h.x, 0.f); h.y = fmaxf(h.y, 0.f);
            h.z = fmaxf(h.z, 0.f); h.w = fmaxf(h.w, 0.f);
        }
        if (lane == 0) dinvS[lrow] = di;
        split_write(Ahi, Alo, h, lrow, l32, half);
    }
    __syncthreads();
    mfma_phase(Ahi, Alo, Wf, dinvS, Gout, base, N, w, lane);
}

// fused hidden step: quarter-split padded gather + relu + split-bf16 MFMA GEMM
__global__ __launch_bounds__(512) void fused_kernel(const int* __restrict__ cnt,
                                                    const int* __restrict__ csr,
                                                    const _Float16* __restrict__ Gin,
                                                    const unsigned short* __restrict__ Wf,
                                                    const float* __restrict__ dinv,
                                                    const float* __restrict__ b,
                                                    _Float16* __restrict__ Gout, int N) {
    __shared__ unsigned short Ahi[16 * 128];
    __shared__ unsigned short Alo[16 * 128];
    __shared__ float dinvS[16];
    int tid = threadIdx.x;
    int w = tid >> 6, lane = tid & 63, q = lane >> 4, l16 = lane & 15;
    long long base = (long long)blockIdx.x * 16;
    const half8* G8 = (const half8*)Gin;    // row = 16 half8s
#pragma unroll
    for (int rr = 0; rr < 2; ++rr) {
        int lrow = w + rr * 8;
        long long node = base + lrow;
        Acc8 r;
#pragma unroll
        for (int k = 0; k < 8; ++k) r.a[k] = 0.f;
        if (node < N) r = gather_q(cnt, csr, G8, node, q, l16);
        // combine quarters (lanes l16, l16+16, l16+32, l16+48)
#pragma unroll
        for (int k = 0; k < 8; ++k) {
            r.a[k] += __shfl_xor(r.a[k], 16);
            r.a[k] += __shfl_xor(r.a[k], 32);
        }
        float di = 0.f;
        float a[8];
        if (node < N) {
            di = dinv[node];
            const float* bp = b + l16 * 8;
#pragma unroll
            for (int k = 0; k < 8; ++k) a[k] = fmaxf(fmaf(r.a[k], di, bp[k]), 0.f);
        } else {
#pragma unroll
            for (int k = 0; k < 8; ++k) a[k] = 0.f;
        }
        unsigned short hb[8];
#pragma unroll
        for (int k = 0; k < 8; ++k) hb[k] = f2bf(a[k]);
        int off = lrow * 128 + ((l16 ^ (lrow & 7)) << 3);
        if (q == 0) {           // hi plane: 16B per lane
            uint4 pk;
            pk.x = (unsigned)hb[0] | ((unsigned)hb[1] << 16);
            pk.y = (unsigned)hb[2] | ((unsigned)hb[3] << 16);
            pk.z = (unsigned)hb[4] | ((unsigned)hb[5] << 16);
            pk.w = (unsigned)hb[6] | ((unsigned)hb[7] << 16);
            *(uint4*)&Ahi[off] = pk;
        } else if (q == 1) {    // lo plane
            unsigned short lb[8];
#pragma unroll
            for (int k = 0; k < 8; ++k) lb[k] = f2bf(a[k] - bf2f(hb[k]));
            uint4 pk;
            pk.x = (unsigned)lb[0] | ((unsigned)lb[1] << 16);
            pk.y = (unsigned)lb[2] | ((unsigned)lb[3] << 16);
            pk.z = (unsigned)lb[4] | ((unsigned)lb[5] << 16);
            pk.w = (unsigned)lb[6] | ((unsigned)lb[7] << 16);
            *(uint4*)&Alo[off] = pk;
        }
        if (lane == 0) dinvS[lrow] = di;
    }
    __syncthreads();
    mfma_phase(Ahi, Alo, Wf, dinvS, Gout, base, N, w, lane);
}

// g4dec: quarter-split padded gather + relu + 128->3 decoder dot (wave per dst)
__global__ __launch_bounds__(256) void g4dec_kernel(const int* __restrict__ cnt,
                                                    const int* __restrict__ csr,
                                                    const _Float16* __restrict__ Gin,
                                                    const float* __restrict__ dinv,
                                                    const float* __restrict__ bh,
                                                    const float* __restrict__ Wdec,
                                                    float* __restrict__ T3g, int N) {
    __shared__ float Wd[384];
    int tid = threadIdx.x;
    for (int i = tid; i < 384; i += 256) Wd[i] = Wdec[i];
    __syncthreads();
    long long wv = ((long long)blockIdx.x * 256 + tid) >> 6;
    if (wv >= N) return;
    int lane = tid & 63, q = lane >> 4, l16 = lane & 15;
    Acc8 r = gather_q(cnt, csr, (const half8*)Gin, wv, q, l16);
#pragma unroll
    for (int k = 0; k < 8; ++k) {
        r.a[k] += __shfl_xor(r.a[k], 16);
        r.a[k] += __shfl_xor(r.a[k], 32);
    }
    float di = dinv[wv];
    const float* bp = bh + l16 * 8;
    float h[8];
#pragma unroll
    for (int k = 0; k < 8; ++k) h[k] = fmaxf(fmaf(r.a[k], di, bp[k]), 0.f);
    int c0 = l16 * 8;
    float p0 = 0.f, p1 = 0.f, p2 = 0.f;
#pragma unroll
    for (int k = 0; k < 8; ++k) {
        p0 = fmaf(h[k], Wd[(c0 + k) * 3 + 0], p0);
        p1 = fmaf(h[k], Wd[(c0 + k) * 3 + 1], p1);
        p2 = fmaf(h[k], Wd[(c0 + k) * 3 + 2], p2);
    }
#pragma unroll
    for (int o = 1; o < 16; o <<= 1) {
        p0 += __shfl_xor(p0, o);
        p1 += __shfl_xor(p1, o);
        p2 += __shfl_xor(p2, o);
    }
    if (lane == 0) {
        T3g[wv * 3 + 0] = p0 * di;
        T3g[wv * 3 + 1] = p1 * di;
        T3g[wv * 3 + 2] = p2 * di;
    }
}

// decoder aggregation (3-wide), thread per dst (stops at true deg)
__global__ void gather3_kernel(const int* __restrict__ cnt, const int* __restrict__ csr,
                               const float* __restrict__ T3g, const float* __restrict__ dinv,
                               const float* __restrict__ b, float* __restrict__ out, int N) {
    int i = blockIdx.x * blockDim.x + threadIdx.x;
    if (i >= N) return;
    int deg = cnt[i]; deg = deg < MAXDEG ? deg : MAXDEG;
    const int* row = csr + ((long long)i << 6);
    const float* ti = T3g + (long long)i * 3;
    float a0 = ti[0], a1 = ti[1], a2 = ti[2];   // self
    for (int j = 0; j < deg; ++j) {
        int src = row[j];
        const float* ts = T3g + (long long)src * 3;
        a0 += ts[0]; a1 += ts[1]; a2 += ts[2];
    }
    float di = dinv[i];
    float* o = out + (long long)i * 3;
    o[0] = fmaf(a0, di, b[0]);
    o[1] = fmaf(a1, di, b[1]);
    o[2] = fmaf(a2, di, b[2]);
}

extern "C" void kernel_launch(void* const* d_in, const int* in_sizes, int n_in,
                              void* d_out, int out_size, void* d_ws, size_t ws_size,
                              hipStream_t stream) {
    const float* x     = (const float*)d_in[0];
    const void* eidx   = d_in[1];
    const float* W_enc = (const float*)d_in[2];
    const float* b_enc = (const float*)d_in[3];
    const float* W_hid = (const float*)d_in[4];
    const float* b_hid = (const float*)d_in[5];
    const float* W_dec = (const float*)d_in[6];
    const float* b_dec = (const float*)d_in[7];

    const int N = in_sizes[0] / 6;          // 100000
    const long long E = in_sizes[1] / 2;    // 1600000
    const int NBLK = (N + 255) / 256;

    char* ws = (char*)d_ws;
    size_t off = 0;
    auto alloc = [&](size_t bytes) { char* p = ws + off; off += (bytes + 255) & ~(size_t)255; return p; };
    int*            flag   = (int*)alloc(4);
    float*          dinv   = (float*)alloc((size_t)N * 4);
    int*            cnt    = (int*)alloc((size_t)N * 4);
    unsigned short* Wf     = (unsigned short*)alloc(2 * 16384 * 2);
    int*            csr    = (int*)alloc((size_t)N * MAXDEG * 4);       // padded CSR
    float*          aggV   = (float*)alloc((size_t)N * 6 * 4);          // enc agg; reused as T3g
    _Float16*       G1     = (_Float16*)alloc(((size_t)N + 1) * HID * 2); // +1 zero row (sentinel)
    _Float16*       G2     = (_Float16*)alloc(((size_t)N + 1) * HID * 2);

    detect_kernel<<<1, 64, 0, stream>>>((const unsigned int*)eidx, E * 2, flag);

    // padded-CSR build: memset cnt -> single atomic pass -> dinv + row padding
    hipMemsetAsync(cnt, 0, (size_t)N * 4, stream);
    build_kernel<<<(int)((E + 255) / 256), 256, 0, stream>>>(eidx, E, flag, cnt, csr);
    dinvpad_kernel<<<NBLK, 256, 0, stream>>>(cnt, dinv, csr, N);

    // zero sentinel row N of both G planes (pads read it)
    hipMemsetAsync(G1 + (size_t)N * HID, 0, HID * 2, stream);
    hipMemsetAsync(G2 + (size_t)N * HID, 0, HID * 2, stream);

    // W_hid fragment prep
    wprep_kernel<<<64, 256, 0, stream>>>(W_hid, Wf);

    // encoder: aggregate x, then fused enc-matmul + gemm1 -> G1
    gather6_kernel<<<NBLK, 256, 0, stream>>>(cnt, csr, x, dinv, aggV, N);
    const int FGRID = (N + 15) / 16;
    encF_kernel<<<FGRID, 512, 0, stream>>>(aggV, W_enc, b_enc, Wf, dinv, G1, N);

    // 3 fused hidden steps: gather+relu+gemm
    fused_kernel<<<FGRID, 512, 0, stream>>>(cnt, csr, G1, Wf, dinv, b_hid, G2, N);
    fused_kernel<<<FGRID, 512, 0, stream>>>(cnt, csr, G2, Wf, dinv, b_hid, G1, N);
    fused_kernel<<<FGRID, 512, 0, stream>>>(cnt, csr, G1, Wf, dinv, b_hid, G2, N);

    // 4th gather fused with decoder matmul -> T3g (aggV), then 3-wide aggregate
    g4dec_kernel<<<(N + 3) / 4, 256, 0, stream>>>(cnt, csr, G2, dinv, b_hid, W_dec, aggV, N);
    gather3_kernel<<<NBLK, 256, 0, stream>>>(cnt, csr, aggV, dinv, b_dec, (float*)d_out, N);
}

// Round 9
// 489.295 us; speedup vs baseline: 1.0643x; 1.0643x over previous
//
#include <hip/hip_runtime.h>

// MeshGNN: 6-layer GCN on 100k nodes / 1.6M edges, HIDDEN=128.
// Round 9: revert r8's padded-build regression -> r7 split CSR build
// (rank -> scans -> fill2, compact CSR; scattered-write passes decoupled).
// Keep r7 fused kernels. Salvage r8's one win: g4dec uses quarter-split
// 16B half8 gather (was 8B half4).

#define HID 128

typedef __attribute__((ext_vector_type(4))) float f32x4;
typedef __attribute__((ext_vector_type(8))) short bf16x8;
typedef __attribute__((ext_vector_type(8))) _Float16 half8;

__device__ __forceinline__ long long ld_idx(const void* p, long long i, int is64) {
    if (is64) return ((const long long*)p)[i];
    return (long long)((const int*)p)[i];
}

__device__ __forceinline__ unsigned short f2bf(float v) {
    unsigned u = __float_as_uint(v);
    unsigned r = (u + 0x7fffu + ((u >> 16) & 1u)) >> 16;
    return (unsigned short)r;
}
__device__ __forceinline__ float bf2f(unsigned short h) {
    return __uint_as_float(((unsigned)h) << 16);
}

// Probe int64 vs int32 edge layout (parallel: 64 lanes x 2 odd words each).
__global__ void detect_kernel(const unsigned int* e, long long nwords, int* flag) {
    int t = threadIdx.x;
    unsigned v = 0;
    long long i0 = 1 + 2 * (long long)t;
    long long i1 = 1 + 2 * (long long)(t + 64);
    if (i0 < nwords && i0 < 256) v |= e[i0];
    if (i1 < nwords && i1 < 256) v |= e[i1];
    int any = __any(v != 0u);
    if (t == 0) *flag = any ? 0 : 1;
}

// pass A: histogram + per-edge rank (single atomic pass; rank write coalesced)
__global__ void rank_kernel(const void* eidx, long long E, const int* flag,
                            int* __restrict__ cnt, int* __restrict__ rank) {
    long long i = (long long)blockIdx.x * blockDim.x + threadIdx.x;
    if (i >= E) return;
    int is64 = *flag;
    int d = (int)ld_idx(eidx, E + i, is64);
    rank[i] = atomicAdd(&cnt[d], 1);
}

// exclusive scan of cnt[N] -> rowptr[N]; also emits dinv = rsqrt(cnt+1)
__global__ void scan1_kernel(const int* cnt, int* rowptr, int* bsum, float* dinv, int N) {
    __shared__ int s[256];
    int i = blockIdx.x * 256 + threadIdx.x;
    int v = (i < N) ? cnt[i] : 0;
    if (i < N) dinv[i] = rsqrtf((float)v + 1.0f);
    s[threadIdx.x] = v;
    __syncthreads();
    for (int off = 1; off < 256; off <<= 1) {
        int t = (threadIdx.x >= off) ? s[threadIdx.x - off] : 0;
        __syncthreads();
        s[threadIdx.x] += t;
        __syncthreads();
    }
    if (i < N) rowptr[i] = s[threadIdx.x] - v;   // exclusive
    if (threadIdx.x == 255) bsum[blockIdx.x] = s[255];
}

__global__ void scan2_kernel(int* bsum, int nb, int* rowptrN, long long E) {
    __shared__ int s[512];
    int t = threadIdx.x;
    int v = (t < nb) ? bsum[t] : 0;
    s[t] = v;
    __syncthreads();
    for (int off = 1; off < 512; off <<= 1) {
        int u = (t >= off) ? s[t - off] : 0;
        __syncthreads();
        s[t] += u;
        __syncthreads();
    }
    if (t < nb) bsum[t] = s[t] - v;
    if (t == 0) *rowptrN = (int)E;
}

__global__ void scan3_kernel(int* rowptr, const int* bsum, int N) {
    int i = blockIdx.x * 256 + threadIdx.x;
    if (i < N) rowptr[i] += bsum[blockIdx.x];
}

// pass B: scatter src into CSR slot (no atomics)
__global__ void fill2_kernel(const void* eidx, long long E, const int* flag,
                             const int* __restrict__ rowptr, const int* __restrict__ rank,
                             int* __restrict__ csr) {
    long long i = (long long)blockIdx.x * blockDim.x + threadIdx.x;
    if (i >= E) return;
    int is64 = *flag;
    int s = (int)ld_idx(eidx, i, is64);
    int d = (int)ld_idx(eidx, E + i, is64);
    csr[rowptr[d] + rank[i]] = s;
}

// encoder aggregation (6-wide), thread per dst
__global__ void gather6_kernel(const int* __restrict__ rowptr, const int* __restrict__ csr,
                               const float* __restrict__ x, const float* __restrict__ dinv,
                               float* __restrict__ aggV, int N) {
    int i = blockIdx.x * blockDim.x + threadIdx.x;
    if (i >= N) return;
    int s = rowptr[i], e = rowptr[i + 1];
    float di = dinv[i];
    const float* xi = x + (long long)i * 6;
    float a0 = xi[0] * di, a1 = xi[1] * di, a2 = xi[2] * di;
    float a3 = xi[3] * di, a4 = xi[4] * di, a5 = xi[5] * di;
    for (int j = s; j < e; ++j) {
        int src = csr[j];
        float ds = dinv[src];
        const float* xs = x + (long long)src * 6;
        a0 += xs[0] * ds; a1 += xs[1] * ds; a2 += xs[2] * ds;
        a3 += xs[3] * ds; a4 += xs[4] * ds; a5 += xs[5] * ds;
    }
    float* o = aggV + (long long)i * 6;
    o[0] = a0 * di; o[1] = a1 * di; o[2] = a2 * di;
    o[3] = a3 * di; o[4] = a4 * di; o[5] = a5 * di;
}

// W_hid -> fragment-ordered split-bf16 (unchanged layout)
__global__ void wprep_kernel(const float* __restrict__ W, unsigned short* __restrict__ Wf) {
    int idx = blockIdx.x * 256 + threadIdx.x;
    if (idx >= 16384) return;
    int j = idx & 7;
    int lane = (idx >> 3) & 63;
    int ks = (idx >> 9) & 3;
    int nt = idx >> 11;
    int c = (nt << 4) + (lane & 15);
    int k = (ks << 5) + ((lane >> 4) << 3) + j;
    float v = W[k * 128 + c];
    unsigned short hi = f2bf(v);
    unsigned short lo = f2bf(v - bf2f(hi));
    Wf[idx] = hi;
    Wf[idx + 16384] = lo;
}

// ---- shared device pieces ----

// quarter-split compact gather: lane (q=lane>>4, l16=lane&15) owns 8 cols of
// srcs with slot ≡ q (mod 4); 16B half8 loads; tail divergence <=1 iter.
struct Acc8 { float a[8]; };
__device__ __forceinline__ Acc8 gather_q(const int* __restrict__ rowptr,
                                         const int* __restrict__ csr,
                                         const half8* __restrict__ G8,
                                         long long node, int q, int l16) {
    Acc8 r;
#pragma unroll
    for (int k = 0; k < 8; ++k) r.a[k] = 0.f;
    int s = rowptr[node], e = rowptr[node + 1];
    int deg = e - s;
    if (q == 0) {                       // self term on quarter 0
        half8 sv = G8[node * 16 + l16];
#pragma unroll
        for (int k = 0; k < 8; ++k) r.a[k] = (float)sv[k];
    }
    int n16 = deg >> 4;
    const int* cs = csr + s + q;
    for (int it = 0; it < n16; ++it) {
        int i0 = cs[0], i1 = cs[4], i2 = cs[8], i3 = cs[12];
        half8 v0 = G8[(long long)i0 * 16 + l16];
        half8 v1 = G8[(long long)i1 * 16 + l16];
        half8 v2 = G8[(long long)i2 * 16 + l16];
        half8 v3 = G8[(long long)i3 * 16 + l16];
#pragma unroll
        for (int k = 0; k < 8; ++k)
            r.a[k] += ((float)v0[k] + (float)v1[k]) + ((float)v2[k] + (float)v3[k]);
        cs += 16;
    }
    for (int j = s + (deg & ~15) + q; j < e; j += 4) {   // tail
        int i0 = csr[j];
        half8 v = G8[(long long)i0 * 16 + l16];
#pragma unroll
        for (int k = 0; k < 8; ++k) r.a[k] += (float)v[k];
    }
    return r;
}

// MFMA phase: 16 rows (LDS split-bf16) x W_hid-fragments -> Gout fp16, x dinv[row]
__device__ __forceinline__ void mfma_phase(const unsigned short* Ahi, const unsigned short* Alo,
                                           const unsigned short* __restrict__ Wf,
                                           const float* dinvS, _Float16* __restrict__ Gout,
                                           long long base, int N, int w, int lane) {
    int arow = lane & 15;
    int abase = arow * 128;
    f32x4 acc = {};
    const bf16x8* Bf = (const bf16x8*)Wf;
#pragma unroll
    for (int ks = 0; ks < 4; ++ks) {
        int slot = (ks << 2) + (lane >> 4);
        int aoff = abase + ((slot ^ (arow & 7)) << 3);
        bf16x8 ah = *(const bf16x8*)&Ahi[aoff];
        bf16x8 al = *(const bf16x8*)&Alo[aoff];
        int g = (((w << 2) + ks) << 6) + lane;
        bf16x8 bh = Bf[g];
        bf16x8 bl = Bf[g + 2048];
        acc = __builtin_amdgcn_mfma_f32_16x16x32_bf16(ah, bh, acc, 0, 0, 0);
        acc = __builtin_amdgcn_mfma_f32_16x16x32_bf16(ah, bl, acc, 0, 0, 0);
        acc = __builtin_amdgcn_mfma_f32_16x16x32_bf16(al, bh, acc, 0, 0, 0);
    }
    int rbase = (lane >> 4) << 2;
    int col = (w << 4) + (lane & 15);
#pragma unroll
    for (int r = 0; r < 4; ++r) {
        int lrow = rbase + r;
        long long grow = base + lrow;
        if (grow < N) Gout[grow * HID + col] = (_Float16)(acc[r] * dinvS[lrow]);
    }
}

// parity split-write (8B per half), used by encF
__device__ __forceinline__ void split_write(unsigned short* Ahi, unsigned short* Alo,
                                            float4 h, int lrow, int l32, int half) {
    unsigned short h0 = f2bf(h.x), h1 = f2bf(h.y), h2 = f2bf(h.z), h3 = f2bf(h.w);
    int slot = l32 >> 1;
    int off = lrow * 128 + (((slot ^ (lrow & 7)) << 3) | ((l32 & 1) << 2));
    if (half == 0) {
        *(uint2*)&Ahi[off] = make_uint2((unsigned)h0 | ((unsigned)h1 << 16),
                                        (unsigned)h2 | ((unsigned)h3 << 16));
    } else {
        unsigned short l0 = f2bf(h.x - bf2f(h0));
        unsigned short l1 = f2bf(h.y - bf2f(h1));
        unsigned short l2 = f2bf(h.z - bf2f(h2));
        unsigned short l3 = f2bf(h.w - bf2f(h3));
        *(uint2*)&Alo[off] = make_uint2((unsigned)l0 | ((unsigned)l1 << 16),
                                        (unsigned)l2 | ((unsigned)l3 << 16));
    }
}

// encF: h0 = relu(aggV @ W_enc + b_enc); G1 = (h0 @ W_hid) * dinv  (16 nodes/block)
__global__ __launch_bounds__(512) void encF_kernel(const float* __restrict__ aggV,
                                                   const float* __restrict__ Wenc,
                                                   const float* __restrict__ benc,
                                                   const unsigned short* __restrict__ Wf,
                                                   const float* __restrict__ dinv,
                                                   _Float16* __restrict__ Gout, int N) {
    __shared__ unsigned short Ahi[16 * 128];
    __shared__ unsigned short Alo[16 * 128];
    __shared__ float WencS[6 * 128];
    __shared__ float dinvS[16];
    int tid = threadIdx.x;
    for (int i = tid; i < 768; i += 512) WencS[i] = Wenc[i];
    __syncthreads();
    int w = tid >> 6, lane = tid & 63, half = lane >> 5, l32 = lane & 31;
    long long base = (long long)blockIdx.x * 16;
#pragma unroll
    for (int rr = 0; rr < 2; ++rr) {
        int lrow = w + rr * 8;
        long long node = base + lrow;
        float4 h = make_float4(0.f, 0.f, 0.f, 0.f);
        float di = 0.f;
        if (node < N) {
            di = dinv[node];
            const float* av = aggV + node * 6;
            float a0 = av[0], a1 = av[1], a2 = av[2], a3 = av[3], a4 = av[4], a5 = av[5];
            float4 bb = *(const float4*)&benc[l32 * 4];
            int c = l32 * 4;
            h = bb;
#define EK(AK, K)                                                   \
            h.x = fmaf(AK, WencS[(K) * 128 + c + 0], h.x);          \
            h.y = fmaf(AK, WencS[(K) * 128 + c + 1], h.y);          \
            h.z = fmaf(AK, WencS[(K) * 128 + c + 2], h.z);          \
            h.w = fmaf(AK, WencS[(K) * 128 + c + 3], h.w);
            EK(a0, 0) EK(a1, 1) EK(a2, 2) EK(a3, 3) EK(a4, 4) EK(a5, 5)
#undef EK
            h.x = fmaxf(h.x, 0.f); h.y = fmaxf(h.y, 0.f);
            h.z = fmaxf(h.z, 0.f); h.w = fmaxf(h.w, 0.f);
        }
        if (lane == 0) dinvS[lrow] = di;
        split_write(Ahi, Alo, h, lrow, l32, half);
    }
    __syncthreads();
    mfma_phase(Ahi, Alo, Wf, dinvS, Gout, base, N, w, lane);
}

// fused hidden step: quarter-split gather + relu + split-bf16 MFMA GEMM
__global__ __launch_bounds__(512) void fused_kernel(const int* __restrict__ rowptr,
                                                    const int* __restrict__ csr,
                                                    const _Float16* __restrict__ Gin,
                                                    const unsigned short* __restrict__ Wf,
                                                    const float* __restrict__ dinv,
                                                    const float* __restrict__ b,
                                                    _Float16* __restrict__ Gout, int N) {
    __shared__ unsigned short Ahi[16 * 128];
    __shared__ unsigned short Alo[16 * 128];
    __shared__ float dinvS[16];
    int tid = threadIdx.x;
    int w = tid >> 6, lane = tid & 63, q = lane >> 4, l16 = lane & 15;
    long long base = (long long)blockIdx.x * 16;
    const half8* G8 = (const half8*)Gin;    // row = 16 half8s
#pragma unroll
    for (int rr = 0; rr < 2; ++rr) {
        int lrow = w + rr * 8;
        long long node = base + lrow;
        Acc8 r;
#pragma unroll
        for (int k = 0; k < 8; ++k) r.a[k] = 0.f;
        if (node < N) r = gather_q(rowptr, csr, G8, node, q, l16);
#pragma unroll
        for (int k = 0; k < 8; ++k) {
            r.a[k] += __shfl_xor(r.a[k], 16);
            r.a[k] += __shfl_xor(r.a[k], 32);
        }
        float di = 0.f;
        float a[8];
        if (node < N) {
            di = dinv[node];
            const float* bp = b + l16 * 8;
#pragma unroll
            for (int k = 0; k < 8; ++k) a[k] = fmaxf(fmaf(r.a[k], di, bp[k]), 0.f);
        } else {
#pragma unroll
            for (int k = 0; k < 8; ++k) a[k] = 0.f;
        }
        unsigned short hb[8];
#pragma unroll
        for (int k = 0; k < 8; ++k) hb[k] = f2bf(a[k]);
        int off = lrow * 128 + ((l16 ^ (lrow & 7)) << 3);
        if (q == 0) {           // hi plane: 16B per lane
            uint4 pk;
            pk.x = (unsigned)hb[0] | ((unsigned)hb[1] << 16);
            pk.y = (unsigned)hb[2] | ((unsigned)hb[3] << 16);
            pk.z = (unsigned)hb[4] | ((unsigned)hb[5] << 16);
            pk.w = (unsigned)hb[6] | ((unsigned)hb[7] << 16);
            *(uint4*)&Ahi[off] = pk;
        } else if (q == 1) {    // lo plane
            unsigned short lb[8];
#pragma unroll
            for (int k = 0; k < 8; ++k) lb[k] = f2bf(a[k] - bf2f(hb[k]));
            uint4 pk;
            pk.x = (unsigned)lb[0] | ((unsigned)lb[1] << 16);
            pk.y = (unsigned)lb[2] | ((unsigned)lb[3] << 16);
            pk.z = (unsigned)lb[4] | ((unsigned)lb[5] << 16);
            pk.w = (unsigned)lb[6] | ((unsigned)lb[7] << 16);
            *(uint4*)&Alo[off] = pk;
        }
        if (lane == 0) dinvS[lrow] = di;
    }
    __syncthreads();
    mfma_phase(Ahi, Alo, Wf, dinvS, Gout, base, N, w, lane);
}

// g4dec: quarter-split 16B gather + relu + 128->3 decoder dot (wave per dst)
__global__ __launch_bounds__(256) void g4dec_kernel(const int* __restrict__ rowptr,
                                                    const int* __restrict__ csr,
                                                    const _Float16* __restrict__ Gin,
                                                    const float* __restrict__ dinv,
                                                    const float* __restrict__ bh,
                                                    const float* __restrict__ Wdec,
                                                    float* __restrict__ T3g, int N) {
    __shared__ float Wd[384];
    int tid = threadIdx.x;
    for (int i = tid; i < 384; i += 256) Wd[i] = Wdec[i];
    __syncthreads();
    long long wv = ((long long)blockIdx.x * 256 + tid) >> 6;
    if (wv >= N) return;
    int lane = tid & 63, q = lane >> 4, l16 = lane & 15;
    Acc8 r = gather_q(rowptr, csr, (const half8*)Gin, wv, q, l16);
#pragma unroll
    for (int k = 0; k < 8; ++k) {
        r.a[k] += __shfl_xor(r.a[k], 16);
        r.a[k] += __shfl_xor(r.a[k], 32);
    }
    float di = dinv[wv];
    const float* bp = bh + l16 * 8;
    float h[8];
#pragma unroll
    for (int k = 0; k < 8; ++k) h[k] = fmaxf(fmaf(r.a[k], di, bp[k]), 0.f);
    int c0 = l16 * 8;
    float p0 = 0.f, p1 = 0.f, p2 = 0.f;
#pragma unroll
    for (int k = 0; k < 8; ++k) {
        p0 = fmaf(h[k], Wd[(c0 + k) * 3 + 0], p0);
        p1 = fmaf(h[k], Wd[(c0 + k) * 3 + 1], p1);
        p2 = fmaf(h[k], Wd[(c0 + k) * 3 + 2], p2);
    }
#pragma unroll
    for (int o = 1; o < 16; o <<= 1) {
        p0 += __shfl_xor(p0, o);
        p1 += __shfl_xor(p1, o);
        p2 += __shfl_xor(p2, o);
    }
    if (lane == 0) {
        T3g[wv * 3 + 0] = p0 * di;
        T3g[wv * 3 + 1] = p1 * di;
        T3g[wv * 3 + 2] = p2 * di;
    }
}

// decoder aggregation (3-wide), thread per dst: out = dinv*(sum + self) + b
__global__ void gather3_kernel(const int* __restrict__ rowptr, const int* __restrict__ csr,
                               const float* __restrict__ T3g, const float* __restrict__ dinv,
                               const float* __restrict__ b, float* __restrict__ out, int N) {
    int i = blockIdx.x * blockDim.x + threadIdx.x;
    if (i >= N) return;
    int s = rowptr[i], e = rowptr[i + 1];
    const float* ti = T3g + (long long)i * 3;
    float a0 = ti[0], a1 = ti[1], a2 = ti[2];   // self
    for (int j = s; j < e; ++j) {
        int src = csr[j];
        const float* ts = T3g + (long long)src * 3;
        a0 += ts[0]; a1 += ts[1]; a2 += ts[2];
    }
    float di = dinv[i];
    float* o = out + (long long)i * 3;
    o[0] = fmaf(a0, di, b[0]);
    o[1] = fmaf(a1, di, b[1]);
    o[2] = fmaf(a2, di, b[2]);
}

extern "C" void kernel_launch(void* const* d_in, const int* in_sizes, int n_in,
                              void* d_out, int out_size, void* d_ws, size_t ws_size,
                              hipStream_t stream) {
    const float* x     = (const float*)d_in[0];
    const void* eidx   = d_in[1];
    const float* W_enc = (const float*)d_in[2];
    const float* b_enc = (const float*)d_in[3];
    const float* W_hid = (const float*)d_in[4];
    const float* b_hid = (const float*)d_in[5];
    const float* W_dec = (const float*)d_in[6];
    const float* b_dec = (const float*)d_in[7];

    const int N = in_sizes[0] / 6;          // 100000
    const long long E = in_sizes[1] / 2;    // 1600000
    const int NBLK = (N + 255) / 256;       // 391 (<= 512 for scan2)

    char* ws = (char*)d_ws;
    size_t off = 0;
    auto alloc = [&](size_t bytes) { char* p = ws + off; off += (bytes + 255) & ~(size_t)255; return p; };
    int*            flag   = (int*)alloc(4);
    float*          dinv   = (float*)alloc((size_t)N * 4);
    int*            cnt    = (int*)alloc((size_t)N * 4);
    int*            rowptr = (int*)alloc(((size_t)N + 1) * 4);
    int*            bsum   = (int*)alloc(2048 * 4);
    unsigned short* Wf     = (unsigned short*)alloc(2 * 16384 * 2);
    int*            csr    = (int*)alloc((size_t)E * 4);
    int*            rank   = (int*)alloc((size_t)E * 4);
    float*          aggV   = (float*)alloc((size_t)N * 6 * 4);      // enc agg; reused as T3g
    _Float16*       G1     = (_Float16*)alloc((size_t)N * HID * 2); // fp16 message planes
    _Float16*       G2     = (_Float16*)alloc((size_t)N * HID * 2);

    detect_kernel<<<1, 64, 0, stream>>>((const unsigned int*)eidx, E * 2, flag);

    // CSR build: rank pass -> scan (emits dinv) -> non-atomic fill
    hipMemsetAsync(cnt, 0, (size_t)N * 4, stream);
    rank_kernel<<<(int)((E + 255) / 256), 256, 0, stream>>>(eidx, E, flag, cnt, rank);
    scan1_kernel<<<NBLK, 256, 0, stream>>>(cnt, rowptr, bsum, dinv, N);
    scan2_kernel<<<1, 512, 0, stream>>>(bsum, NBLK, rowptr + N, E);
    scan3_kernel<<<NBLK, 256, 0, stream>>>(rowptr, bsum, N);
    fill2_kernel<<<(int)((E + 255) / 256), 256, 0, stream>>>(eidx, E, flag, rowptr, rank, csr);

    // W_hid fragment prep
    wprep_kernel<<<64, 256, 0, stream>>>(W_hid, Wf);

    // encoder: aggregate x, then fused enc-matmul + gemm1 -> G1
    gather6_kernel<<<NBLK, 256, 0, stream>>>(rowptr, csr, x, dinv, aggV, N);
    const int FGRID = (N + 15) / 16;
    encF_kernel<<<FGRID, 512, 0, stream>>>(aggV, W_enc, b_enc, Wf, dinv, G1, N);

    // 3 fused hidden steps: gather+relu+gemm
    fused_kernel<<<FGRID, 512, 0, stream>>>(rowptr, csr, G1, Wf, dinv, b_hid, G2, N);
    fused_kernel<<<FGRID, 512, 0, stream>>>(rowptr, csr, G2, Wf, dinv, b_hid, G1, N);
    fused_kernel<<<FGRID, 512, 0, stream>>>(rowptr, csr, G1, Wf, dinv, b_hid, G2, N);

    // 4th gather fused with decoder matmul -> T3g (aggV), then 3-wide aggregate
    g4dec_kernel<<<(N + 3) / 4, 256, 0, stream>>>(rowptr, csr, G2, dinv, b_hid, W_dec, aggV, N);
    gather3_kernel<<<NBLK, 256, 0, stream>>>(rowptr, csr, aggV, dinv, b_dec, (float*)d_out, N);
}